// Round 6
// baseline (519.341 us; speedup 1.0000x reference)
//
#include <hip/hip_runtime.h>
#include <cmath>

#define BB 8
#define HH 512
#define WW 512
#define HW (HH*WW)
#define RAD 15
#define SEG 32
#define EPS 0.001f
#define INV_K (1.0f/31.0f)
#define TROWS 16
#define NPX 272            // computed px per block: 256 out + 16 halo
#define XOFF (-8)

typedef short bf16x8 __attribute__((ext_vector_type(8)));
typedef short bf16x4 __attribute__((ext_vector_type(4)));
typedef float f32x4 __attribute__((ext_vector_type(4)));
typedef float f32x2 __attribute__((ext_vector_type(2)));
typedef int   i32x4 __attribute__((ext_vector_type(4)));
typedef _Float16 h16x2 __attribute__((ext_vector_type(2)));
typedef _Float16 h16x4 __attribute__((ext_vector_type(4)));

static __device__ inline short f2bf(float f) {
    unsigned int u = __float_as_uint(f);
    unsigned int r = (u + 0x7FFFu + ((u >> 16) & 1u)) >> 16;   // RNE
    return (short)r;
}
static __device__ inline float bf2f(short s) {
    return __uint_as_float(((unsigned int)(unsigned short)s) << 16);
}
static __device__ inline int s3(int r) { return (r + 6) % 3; }   // r >= -6

// ---------------- weight fragment prepack (1 wave) ----------------
__global__ __launch_bounds__(64) void k_wprep(const float* __restrict__ W1,
                                              const float* __restrict__ W2,
                                              short* __restrict__ wf1,
                                              short* __restrict__ wf2) {
    int lane = threadIdx.x;
    int j = lane & 15, g = lane >> 4;
#pragma unroll
    for (int cg = 0; cg < 2; ++cg)
#pragma unroll
        for (int t = 0; t < 3; ++t) {
            int s = t * 4 + g;
            bf16x8 w;
#pragma unroll
            for (int i = 0; i < 8; ++i)
                w[i] = (s < 9) ? f2bf(W1[(cg * 16 + j) * 72 + i * 9 + s]) : (short)0;
            *(bf16x8*)(wf1 + ((cg * 3 + t) * 64 + lane) * 8) = w;
        }
    int ci0 = g * 8;
#pragma unroll
    for (int s = 0; s < 9; ++s) {
        bf16x8 w;
#pragma unroll
        for (int i = 0; i < 8; ++i)
            w[i] = f2bf(W2[j * 288 + (ci0 + i) * 9 + s]);
        *(bf16x8*)(wf2 + (s * 64 + lane) * 8) = w;
    }
}

// ------- gray + horizontal box + feats(ch0-2,4-7) -------
__global__ __launch_bounds__(256) void k_gray_hbox4(const float* __restrict__ I,
                                                    const float* __restrict__ p,
                                                    const float* __restrict__ dark,
                                                    const float* __restrict__ A,
                                                    float* __restrict__ g,
                                                    f32x4* __restrict__ hq,
                                                    short* __restrict__ feats) {
    __shared__ float sg[WW], sp[WW];
    int row = blockIdx.x;            // b*HH + y
    int b = row >> 9;
    int base = row * WW;
    const float* Ib = I + (size_t)b * 3 * HW + (size_t)(row & 511) * WW;
    const float* db = dark + (size_t)base;
    short A0 = f2bf(A[b * 3 + 0]), A1 = f2bf(A[b * 3 + 1]), A2 = f2bf(A[b * 3 + 2]);
    int tid = threadIdx.x;
    for (int x = tid; x < WW; x += 256) {
        float i0 = Ib[x], i1 = Ib[HW + x], i2 = Ib[2 * HW + x];
        float gv = 0.299f * i0 + 0.587f * i1 + 0.114f * i2;
        sg[x] = gv; sp[x] = p[base + x];
        g[base + x] = gv;
        bf16x8 v;
        v[0] = f2bf(i0); v[1] = f2bf(i1); v[2] = f2bf(i2);
        v[3] = 0;                       // tg written later by k_vbox2_tg
        v[4] = f2bf(db[x]);
        v[5] = A0; v[6] = A1; v[7] = A2;
        *(bf16x8*)(feats + ((size_t)base + x) * 8) = v;
    }
    __syncthreads();
    for (int x = tid; x < WW; x += 256) {
        float s0 = 0.f, s1 = 0.f, s2 = 0.f, s3v = 0.f;
        int lo = x - RAD < 0 ? 0 : x - RAD;
        int hi = x + RAD >= WW ? WW - 1 : x + RAD;
        for (int i = lo; i <= hi; ++i) {
            float gv = sg[i], pv = sp[i];
            s0 += gv; s1 += pv; s2 += gv * pv; s3v += gv * gv;
        }
        f32x4 o = { s0 * INV_K, s1 * INV_K, s2 * INV_K, s3v * INV_K };
        hq[base + x] = o;
    }
}

// ---------------- vertical box of hq, fused a/b ----------------
__global__ __launch_bounds__(256) void k_vbox4_ab(const f32x4* __restrict__ hq,
                                                  f32x2* __restrict__ ab) {
    int x = blockIdx.x * 256 + threadIdx.x;
    int b = blockIdx.y;
    int y0 = blockIdx.z * SEG;
    int pbase = b * HW + x;
    f32x4 s = { 0.f, 0.f, 0.f, 0.f };
    int r0 = y0 - RAD < 0 ? 0 : y0 - RAD;
    for (int r = r0; r < y0 + RAD; ++r) s += hq[pbase + r * WW];
    for (int y = y0; y < y0 + SEG; ++y) {
        if (y + RAD < HH) s += hq[pbase + (y + RAD) * WW];
        float mI = s[0] * INV_K, mP = s[1] * INV_K, mIp = s[2] * INV_K, mII = s[3] * INV_K;
        float cov = mIp - mI * mP;
        float var = mII - mI * mI;
        float av = cov / (var + EPS);
        float bv = mP - av * mI;
        f32x2 o = { av, bv };
        ab[pbase + y * WW] = o;
        if (y - RAD >= 0) s -= hq[pbase + (y - RAD) * WW];
    }
}

// ---------------- horizontal box of ab ----------------
__global__ __launch_bounds__(256) void k_hbox2(const f32x2* __restrict__ ab,
                                               f32x2* __restrict__ hab) {
    __shared__ float sa[WW], sb[WW];
    int base = blockIdx.x * WW;
    int tid = threadIdx.x;
    for (int x = tid; x < WW; x += 256) {
        f32x2 v = ab[base + x];
        sa[x] = v[0]; sb[x] = v[1];
    }
    __syncthreads();
    for (int x = tid; x < WW; x += 256) {
        float s0 = 0.f, s1 = 0.f;
        int lo = x - RAD < 0 ? 0 : x - RAD;
        int hi = x + RAD >= WW ? WW - 1 : x + RAD;
        for (int i = lo; i <= hi; ++i) { s0 += sa[i]; s1 += sb[i]; }
        f32x2 o = { s0 * INV_K, s1 * INV_K };
        hab[base + x] = o;
    }
}

// ------- vertical box of hab + t_guided -> tg fp32 + feats ch3 -------
__global__ __launch_bounds__(256) void k_vbox2_tg(const f32x2* __restrict__ hab,
                                                  const float* __restrict__ g,
                                                  float* __restrict__ tg,
                                                  short* __restrict__ feats) {
    int x = blockIdx.x * 256 + threadIdx.x;
    int b = blockIdx.y;
    int y0 = blockIdx.z * SEG;
    int pbase = b * HW + x;
    f32x2 s = { 0.f, 0.f };
    int r0 = y0 - RAD < 0 ? 0 : y0 - RAD;
    for (int r = r0; r < y0 + RAD; ++r) s += hab[pbase + r * WW];
    for (int y = y0; y < y0 + SEG; ++y) {
        if (y + RAD < HH) s += hab[pbase + (y + RAD) * WW];
        int o = pbase + y * WW;
        float val = (s[0] * INV_K) * g[o] + (s[1] * INV_K);
        tg[o] = val;
        feats[(size_t)o * 8 + 3] = f2bf(val);
        if (y - RAD >= 0) s -= hab[pbase + (y - RAD) * WW];
    }
}

// ---------------- fused conv1+conv2+conv3 ----------------
// h1 LDS row: [NPX px][32 ch] bf16; 16B granule c (=ch/8) stored at sp = c ^ ((lp>>1)&3)
// -> 8 consecutive px hit 8 distinct granule-slots mod 8: conflict-free ds_read_b128.
static __device__ inline bf16x8 ld_h1(const short* hrow, int lp, int c) {
    int sp = c ^ ((lp >> 1) & 3);
    return *(const bf16x8*)(hrow + lp * 32 + sp * 8);
}
static __device__ inline void st_h1(short* hrow, int lp, int u, bf16x4 o) {   // u = 8B unit (ch/4)
    int sp = (u >> 1) ^ ((lp >> 1) & 3);
    *(bf16x4*)(hrow + lp * 32 + sp * 8 + (u & 1) * 4) = o;
}
// h2 LDS row: [NPX px][16 ch] fp16; 16B granule c (=ch/8) at sp = c ^ ((lp>>2)&1)
static __device__ inline void st_h2(_Float16* hrow, int lp, int u, h16x4 o) { // u = 8B unit (ch/4)
    int sp = (u >> 1) ^ ((lp >> 2) & 1);
    *(h16x4*)(hrow + lp * 16 + sp * 8 + (u & 1) * 4) = o;
}

static __device__ inline void load_b1(const short* fb, int r1, int X0, int g,
                                      int j, int gq, bf16x8 Bg[3]) {
    bool xedgeG = (X0 == 0 && g == 0) || (X0 == 256 && g == 16);
    int gxb = X0 + XOFF + g * 16 + j;
    if (!xedgeG && r1 >= 1 && r1 <= 509) {
#pragma unroll
        for (int t = 0; t < 3; ++t) {
            int s = t * 4 + gq;
            int dy = s / 3 - 1, dx = s - (s / 3) * 3 - 1;
            Bg[t] = *(const bf16x8*)(fb + ((size_t)(r1 + dy) * WW + (gxb + dx)) * 8);
        }
    } else {
        const bf16x8 zerov = {0,0,0,0,0,0,0,0};
#pragma unroll
        for (int t = 0; t < 3; ++t) {
            int s = t * 4 + gq;
            int dy = s / 3 - 1, dx = s - (s / 3) * 3 - 1;
            int yy = r1 + dy, xx = gxb + dx;
            bool ok = (s < 9) && yy >= 0 && yy < HH && xx >= 0 && xx < WW;
            int yc = yy < 0 ? 0 : (yy > HH - 1 ? HH - 1 : yy);
            int xc = xx < 0 ? 0 : (xx > WW - 1 ? WW - 1 : xx);
            bf16x8 v = *(const bf16x8*)(fb + ((size_t)yc * WW + xc) * 8);
            Bg[t] = ok ? v : zerov;
        }
    }
}

static __device__ inline f32x4 conv2_group(const short* hr0, const short* hr1,
                                           const short* hr2, const bf16x8* wA2,
                                           int g, int j, int gq, int X0) {
    f32x4 acc = {0.f, 0.f, 0.f, 0.f};
    const bf16x8 zerov = {0,0,0,0,0,0,0,0};
    int lpb = g * 16 + j;
    const short* rows[3] = {hr0, hr1, hr2};
    if (g != 0 && g != 16) {
#pragma unroll
        for (int dy = 0; dy < 3; ++dy) {
            const short* hrow = rows[dy];
            bf16x8 vm = ld_h1(hrow, lpb - 1, gq);
            bf16x8 v0 = ld_h1(hrow, lpb, gq);
            bf16x8 vp = ld_h1(hrow, lpb + 1, gq);
            acc = __builtin_amdgcn_mfma_f32_16x16x32_bf16(wA2[dy * 3 + 0], vm, acc, 0, 0, 0);
            acc = __builtin_amdgcn_mfma_f32_16x16x32_bf16(wA2[dy * 3 + 1], v0, acc, 0, 0, 0);
            acc = __builtin_amdgcn_mfma_f32_16x16x32_bf16(wA2[dy * 3 + 2], vp, acc, 0, 0, 0);
        }
    } else {
#pragma unroll
        for (int dy = 0; dy < 3; ++dy) {
            const short* hrow = rows[dy];
#pragma unroll
            for (int dx = 0; dx < 3; ++dx) {
                int lpx = lpb + dx - 1;
                int gx = X0 + XOFF + lpx;
                bool ok = (gx >= 0) && (gx < WW);
                int lpc = lpx < 0 ? 0 : (lpx > NPX - 1 ? NPX - 1 : lpx);
                bf16x8 v = ok ? ld_h1(hrow, lpc, gq) : zerov;
                acc = __builtin_amdgcn_mfma_f32_16x16x32_bf16(wA2[dy * 3 + dx], v, acc, 0, 0, 0);
            }
        }
    }
    return acc;
}

__global__ __launch_bounds__(512, 4) void k_cnn_fused(const short* __restrict__ feats,
                                                      const short* __restrict__ wf1,
                                                      const short* __restrict__ wf2,
                                                      const float* __restrict__ b1,
                                                      const float* __restrict__ b2,
                                                      const float* __restrict__ W3,
                                                      const float* __restrict__ b3,
                                                      const float* __restrict__ tg,
                                                      float* __restrict__ out) {
    __shared__ short h1s[3][NPX * 32];       // 52,224 B
    __shared__ _Float16 h2s[3][NPX * 16];    // 26,112 B
    __shared__ h16x2 w3s[72];
    __shared__ float w3bias;

    int tid = threadIdx.x;
    int lane = tid & 63, wave = tid >> 6;
    int j = lane & 15, gq = lane >> 4;
    int b = blockIdx.y;
    int X0 = (blockIdx.x & 1) * 256;
    int y0 = (blockIdx.x >> 1) * TROWS;
    const short* fb = feats + (size_t)b * HW * 8;
    const float* tgb = tg + (size_t)b * HW;
    float* outb = out + (size_t)b * HW;

    const bf16x8* wf1v = (const bf16x8*)wf1;
    const bf16x8* wf2v = (const bf16x8*)wf2;
    bf16x8 wA1[2][3], wA2[9];
#pragma unroll
    for (int cg = 0; cg < 2; ++cg)
#pragma unroll
        for (int t = 0; t < 3; ++t) wA1[cg][t] = wf1v[(cg * 3 + t) * 64 + lane];
#pragma unroll
    for (int s = 0; s < 9; ++s) wA2[s] = wf2v[s * 64 + lane];
    f32x4 bias1[2];
    bias1[0] = *(const f32x4*)(b1 + gq * 4);
    bias1[1] = *(const f32x4*)(b1 + 16 + gq * 4);
    f32x4 bias2 = *(const f32x4*)(b2 + gq * 4);
    if (tid < 72) {
        int s = tid >> 3, u = tid & 7;
        h16x2 w;
        w[0] = (_Float16)W3[(2 * u) * 9 + s];
        w[1] = (_Float16)W3[(2 * u + 1) * 9 + s];
        w3s[tid] = w;
    }
    if (tid == 72) w3bias = b3[0];
    __syncthreads();

    bf16x8 Bv[2][3];     // prefetched conv1 B-frags, groups {wave*2, wave*2+1}
    bf16x8 Bg16[3];      // group 16 (wave 0 only)
    const i32x4 zz = {0, 0, 0, 0};

    for (int i = 0; i < TROWS + 5; ++i) {
        int r1 = y0 + i - 2;              // h1 row computed this iter
        int r2 = y0 + i - 4;              // h2 row
        int r3 = y0 + i - 5;              // out row
        bool do_h1 = (i <= TROWS + 3);
        bool do_h2 = (i >= 3) && (i <= TROWS + 4);
        bool do_out = (i >= 5);
        bool h1zero = (r1 < 0) || (r1 > 511);

        // ---- P1a: issue feats global loads for h1 row r1 (prefetch) ----
        if (do_h1 && !h1zero) {
#pragma unroll
            for (int k = 0; k < 2; ++k)
                load_b1(fb, r1, X0, wave * 2 + k, j, gq, Bv[k]);
            if (wave == 0) load_b1(fb, r1, X0, 16, j, gq, Bg16);
        }

        // ---- P1b: conv2 -> h2 row r2 (reads h1 rows r2-1..r2+1 from LDS) ----
        if (do_h2) {
            _Float16* h2row = h2s[s3(r2)];
            if (r2 < 0 || r2 > 511) {
                for (int q = tid; q < 544; q += 512) ((i32x4*)h2row)[q] = zz;
            } else {
                const short* hr0 = h1s[s3(r2 - 1)];
                const short* hr1 = h1s[s3(r2)];
                const short* hr2 = h1s[s3(r2 + 1)];
#pragma unroll
                for (int k = 0; k < 2; ++k) {
                    int g = wave * 2 + k;
                    f32x4 a2 = conv2_group(hr0, hr1, hr2, wA2, g, j, gq, X0);
                    h16x4 o;
#pragma unroll
                    for (int r = 0; r < 4; ++r) o[r] = (_Float16)fmaxf(a2[r] + bias2[r], 0.f);
                    st_h2(h2row, g * 16 + j, gq, o);
                }
                if (wave == 0) {
                    f32x4 a2 = conv2_group(hr0, hr1, hr2, wA2, 16, j, gq, X0);
                    h16x4 o;
#pragma unroll
                    for (int r = 0; r < 4; ++r) o[r] = (_Float16)fmaxf(a2[r] + bias2[r], 0.f);
                    st_h2(h2row, 16 * 16 + j, gq, o);
                }
            }
        }
        __syncthreads();

        // ---- P2a: conv1 MFMA + store h1 row r1 ----
        if (do_h1) {
            short* h1row = h1s[s3(r1)];
            if (h1zero) {
                for (int q = tid; q < 1088; q += 512) ((i32x4*)h1row)[q] = zz;
            } else {
#pragma unroll
                for (int k = 0; k < 2; ++k) {
                    f32x4 a1[2] = {};
#pragma unroll
                    for (int t = 0; t < 3; ++t)
#pragma unroll
                        for (int cg = 0; cg < 2; ++cg)
                            a1[cg] = __builtin_amdgcn_mfma_f32_16x16x32_bf16(wA1[cg][t], Bv[k][t], a1[cg], 0, 0, 0);
                    int lp = (wave * 2 + k) * 16 + j;
#pragma unroll
                    for (int cg = 0; cg < 2; ++cg) {
                        bf16x4 o;
#pragma unroll
                        for (int r = 0; r < 4; ++r) o[r] = f2bf(fmaxf(a1[cg][r] + bias1[cg][r], 0.f));
                        st_h1(h1row, lp, cg * 4 + gq, o);
                    }
                }
                if (wave == 0) {
                    f32x4 a1[2] = {};
#pragma unroll
                    for (int t = 0; t < 3; ++t)
#pragma unroll
                        for (int cg = 0; cg < 2; ++cg)
                            a1[cg] = __builtin_amdgcn_mfma_f32_16x16x32_bf16(wA1[cg][t], Bg16[t], a1[cg], 0, 0, 0);
                    int lp = 16 * 16 + j;
#pragma unroll
                    for (int cg = 0; cg < 2; ++cg) {
                        bf16x4 o;
#pragma unroll
                        for (int r = 0; r < 4; ++r) o[r] = f2bf(fmaxf(a1[cg][r] + bias1[cg][r], 0.f));
                        st_h1(h1row, lp, cg * 4 + gq, o);
                    }
                }
            }
        }

        // ---- P2b: conv3 + sigmoid + blend + clip, out row r3 ----
        if (do_out && tid < 256) {
            int lp = tid + 8;
            float acc = w3bias;
#pragma unroll
            for (int dy = 0; dy < 3; ++dy) {
                const _Float16* hrow = h2s[s3(r3 - 1 + dy)];
#pragma unroll
                for (int dx = 0; dx < 3; ++dx) {
                    int gx = X0 + tid + dx - 1;
                    if (gx >= 0 && gx < WW) {
                        int lpx = lp + dx - 1;
                        int sp = (lpx >> 2) & 1;
                        i32x4 lo = *(const i32x4*)(hrow + lpx * 16 + sp * 8);
                        i32x4 hi = *(const i32x4*)(hrow + lpx * 16 + (1 - sp) * 8);
                        int sb = (dy * 3 + dx) * 8;
#pragma unroll
                        for (int q = 0; q < 4; ++q)
                            acc = __builtin_amdgcn_fdot2(__builtin_bit_cast(h16x2, lo[q]), w3s[sb + q], acc, false);
#pragma unroll
                        for (int q = 0; q < 4; ++q)
                            acc = __builtin_amdgcn_fdot2(__builtin_bit_cast(h16x2, hi[q]), w3s[sb + 4 + q], acc, false);
                    }
                }
            }
            float sg = 1.f / (1.f + expf(-acc));
            int o = r3 * WW + X0 + tid;
            float tf = 0.7f * tgb[o] + 0.3f * sg;
            outb[o] = fminf(fmaxf(tf, 0.f), 1.f);
        }
        __syncthreads();
    }
}

extern "C" void kernel_launch(void* const* d_in, const int* in_sizes, int n_in,
                              void* d_out, int out_size, void* d_ws, size_t ws_size,
                              hipStream_t stream) {
    const float* I    = (const float*)d_in[0];
    const float* t0   = (const float*)d_in[1];
    const float* dark = (const float*)d_in[2];
    const float* A    = (const float*)d_in[3];
    const float* W1   = (const float*)d_in[4];
    const float* b1   = (const float*)d_in[5];
    const float* W2   = (const float*)d_in[6];
    const float* b2   = (const float*)d_in[7];
    const float* W3   = (const float*)d_in[8];
    const float* b3   = (const float*)d_in[9];
    float* out = (float*)d_out;
    float* ws  = (float*)d_ws;

    const size_t P = (size_t)BB * HW;       // 2M floats = 8 MB
    float* tg    = ws;                      // [0,P)   fp32
    short* feats = (short*)(ws + P);        // [P,5P)  bf16 [B][H][W][8]
    float* g     = ws + 5 * P;              // [5P,6P)
    f32x4* hq    = (f32x4*)(ws + 6 * P);    // [6P,10P)
    f32x2* ab    = (f32x2*)(ws + 10 * P);   // [10P,12P)
    f32x2* hab   = (f32x2*)(ws + 12 * P);   // [12P,14P)
    short* wf1   = (short*)(ws + 14 * P);   // 3072 shorts
    short* wf2   = wf1 + 6 * 64 * 8;        // 4608 shorts

    k_wprep<<<1, 64, 0, stream>>>(W1, W2, wf1, wf2);
    k_gray_hbox4<<<BB * HH, 256, 0, stream>>>(I, t0, dark, A, g, hq, feats);
    dim3 gv(WW / 256, BB, HH / SEG);
    k_vbox4_ab<<<gv, 256, 0, stream>>>(hq, ab);
    k_hbox2<<<BB * HH, 256, 0, stream>>>(ab, hab);
    k_vbox2_tg<<<gv, 256, 0, stream>>>(hab, g, tg, feats);

    dim3 gf(64, BB);                        // 32 y-tiles x 2 x-halves x 8 batches = 512 blocks
    k_cnn_fused<<<gf, 512, 0, stream>>>(feats, wf1, wf2, b1, b2, W3, b3, tg, out);
}

// Round 7
// 412.012 us; speedup vs baseline: 1.2605x; 1.2605x over previous
//
#include <hip/hip_runtime.h>
#include <cmath>

#define BB 8
#define HH 512
#define WW 512
#define HW (HH*WW)
#define RAD 15
#define SEG 32
#define EPS 0.001f
#define INV_K (1.0f/31.0f)
#define TROWS 16

typedef _Float16 h16x8 __attribute__((ext_vector_type(8)));
typedef _Float16 h16x4 __attribute__((ext_vector_type(4)));
typedef _Float16 h16x2 __attribute__((ext_vector_type(2)));
typedef float f32x4 __attribute__((ext_vector_type(4)));
typedef float f32x2 __attribute__((ext_vector_type(2)));
typedef int   i32x4 __attribute__((ext_vector_type(4)));

static __device__ inline int s3(int r) { return (r + 6) % 3; }   // r >= -6

// ---------------- weight fragment prepack (1 wave) ----------------
__global__ __launch_bounds__(64) void k_wprep(const float* __restrict__ W1,
                                              const float* __restrict__ W2,
                                              _Float16* __restrict__ wf1,
                                              _Float16* __restrict__ wf2) {
    int lane = threadIdx.x;
    int j = lane & 15, g = lane >> 4;
#pragma unroll
    for (int cg = 0; cg < 2; ++cg)
#pragma unroll
        for (int t = 0; t < 3; ++t) {
            int s = t * 4 + g;
            h16x8 w;
#pragma unroll
            for (int i = 0; i < 8; ++i)
                w[i] = (s < 9) ? (_Float16)W1[(cg * 16 + j) * 72 + i * 9 + s] : (_Float16)0.f;
            *(h16x8*)(wf1 + ((cg * 3 + t) * 64 + lane) * 8) = w;
        }
    int ci0 = g * 8;
#pragma unroll
    for (int s = 0; s < 9; ++s) {
        h16x8 w;
#pragma unroll
        for (int i = 0; i < 8; ++i)
            w[i] = (_Float16)W2[j * 288 + (ci0 + i) * 9 + s];
        *(h16x8*)(wf2 + (s * 64 + lane) * 8) = w;
    }
}

// ------- gray + horizontal box + feats(ch0-2,4-7) fp16 -------
__global__ __launch_bounds__(256) void k_gray_hbox4(const float* __restrict__ I,
                                                    const float* __restrict__ p,
                                                    const float* __restrict__ dark,
                                                    const float* __restrict__ A,
                                                    float* __restrict__ g,
                                                    f32x4* __restrict__ hq,
                                                    _Float16* __restrict__ feats) {
    __shared__ float sg[WW], sp[WW];
    int row = blockIdx.x;            // b*HH + y
    int b = row >> 9;
    int base = row * WW;
    const float* Ib = I + (size_t)b * 3 * HW + (size_t)(row & 511) * WW;
    const float* db = dark + (size_t)base;
    _Float16 A0 = (_Float16)A[b * 3 + 0], A1 = (_Float16)A[b * 3 + 1], A2 = (_Float16)A[b * 3 + 2];
    int tid = threadIdx.x;
    for (int x = tid; x < WW; x += 256) {
        float i0 = Ib[x], i1 = Ib[HW + x], i2 = Ib[2 * HW + x];
        float gv = 0.299f * i0 + 0.587f * i1 + 0.114f * i2;
        sg[x] = gv; sp[x] = p[base + x];
        g[base + x] = gv;
        h16x8 v;
        v[0] = (_Float16)i0; v[1] = (_Float16)i1; v[2] = (_Float16)i2;
        v[3] = (_Float16)0.f;           // tg written later by k_vbox2_tg
        v[4] = (_Float16)db[x];
        v[5] = A0; v[6] = A1; v[7] = A2;
        *(h16x8*)(feats + ((size_t)base + x) * 8) = v;
    }
    __syncthreads();
    for (int x = tid; x < WW; x += 256) {
        float s0 = 0.f, s1 = 0.f, s2 = 0.f, s3v = 0.f;
        int lo = x - RAD < 0 ? 0 : x - RAD;
        int hi = x + RAD >= WW ? WW - 1 : x + RAD;
        for (int i = lo; i <= hi; ++i) {
            float gv = sg[i], pv = sp[i];
            s0 += gv; s1 += pv; s2 += gv * pv; s3v += gv * gv;
        }
        f32x4 o = { s0 * INV_K, s1 * INV_K, s2 * INV_K, s3v * INV_K };
        hq[base + x] = o;
    }
}

// ---------------- vertical box of hq, fused a/b ----------------
__global__ __launch_bounds__(256) void k_vbox4_ab(const f32x4* __restrict__ hq,
                                                  f32x2* __restrict__ ab) {
    int x = blockIdx.x * 256 + threadIdx.x;
    int b = blockIdx.y;
    int y0 = blockIdx.z * SEG;
    int pbase = b * HW + x;
    f32x4 s = { 0.f, 0.f, 0.f, 0.f };
    int r0 = y0 - RAD < 0 ? 0 : y0 - RAD;
    for (int r = r0; r < y0 + RAD; ++r) s += hq[pbase + r * WW];
    for (int y = y0; y < y0 + SEG; ++y) {
        if (y + RAD < HH) s += hq[pbase + (y + RAD) * WW];
        float mI = s[0] * INV_K, mP = s[1] * INV_K, mIp = s[2] * INV_K, mII = s[3] * INV_K;
        float cov = mIp - mI * mP;
        float var = mII - mI * mI;
        float av = cov / (var + EPS);
        float bv = mP - av * mI;
        f32x2 o = { av, bv };
        ab[pbase + y * WW] = o;
        if (y - RAD >= 0) s -= hq[pbase + (y - RAD) * WW];
    }
}

// ---------------- horizontal box of ab ----------------
__global__ __launch_bounds__(256) void k_hbox2(const f32x2* __restrict__ ab,
                                               f32x2* __restrict__ hab) {
    __shared__ float sa[WW], sb[WW];
    int base = blockIdx.x * WW;
    int tid = threadIdx.x;
    for (int x = tid; x < WW; x += 256) {
        f32x2 v = ab[base + x];
        sa[x] = v[0]; sb[x] = v[1];
    }
    __syncthreads();
    for (int x = tid; x < WW; x += 256) {
        float s0 = 0.f, s1 = 0.f;
        int lo = x - RAD < 0 ? 0 : x - RAD;
        int hi = x + RAD >= WW ? WW - 1 : x + RAD;
        for (int i = lo; i <= hi; ++i) { s0 += sa[i]; s1 += sb[i]; }
        f32x2 o = { s0 * INV_K, s1 * INV_K };
        hab[base + x] = o;
    }
}

// ------- vertical box of hab + t_guided -> tg fp32 + feats ch3 fp16 -------
__global__ __launch_bounds__(256) void k_vbox2_tg(const f32x2* __restrict__ hab,
                                                  const float* __restrict__ g,
                                                  float* __restrict__ tg,
                                                  _Float16* __restrict__ feats) {
    int x = blockIdx.x * 256 + threadIdx.x;
    int b = blockIdx.y;
    int y0 = blockIdx.z * SEG;
    int pbase = b * HW + x;
    f32x2 s = { 0.f, 0.f };
    int r0 = y0 - RAD < 0 ? 0 : y0 - RAD;
    for (int r = r0; r < y0 + RAD; ++r) s += hab[pbase + r * WW];
    for (int y = y0; y < y0 + SEG; ++y) {
        if (y + RAD < HH) s += hab[pbase + (y + RAD) * WW];
        int o = pbase + y * WW;
        float val = (s[0] * INV_K) * g[o] + (s[1] * INV_K);
        tg[o] = val;
        feats[(size_t)o * 8 + 3] = (_Float16)val;
        if (y - RAD >= 0) s -= hab[pbase + (y - RAD) * WW];
    }
}

// ---------------- fused conv1+conv2+conv3, full 512-px row ----------------
// h1 row: [512 px][32 ch] fp16; 16B granule c stored at sp = c ^ ((lp>>1)&3)
static __device__ inline h16x8 ld_h1(const _Float16* hrow, int lp, int c) {
    int sp = c ^ ((lp >> 1) & 3);
    return *(const h16x8*)(hrow + lp * 32 + sp * 8);
}
static __device__ inline void st_h1(_Float16* hrow, int lp, int u, h16x4 o) {  // u = ch/4
    int sp = (u >> 1) ^ ((lp >> 1) & 3);
    *(h16x4*)(hrow + lp * 32 + sp * 8 + (u & 1) * 4) = o;
}
// h2 row: [512 px][16 ch] fp16; granule c at sp = c ^ ((lp>>2)&1)
static __device__ inline void st_h2(_Float16* hrow, int lp, int u, h16x4 o) {  // u = ch/4
    int sp = (u >> 1) ^ ((lp >> 2) & 1);
    *(h16x4*)(hrow + lp * 16 + sp * 8 + (u & 1) * 4) = o;
}

static __device__ inline void load_b1(const _Float16* fb, int r1, int g, int j, int gq,
                                      h16x8 Bg[3]) {
    const h16x8 z = {0,0,0,0,0,0,0,0};
    int xb = g * 16 + j;
    if (r1 >= 1 && r1 <= 509 && g != 0 && g != 31) {
#pragma unroll
        for (int t = 0; t < 3; ++t) {
            int s = t * 4 + gq;
            int dy = s / 3 - 1, dx = s - (s / 3) * 3 - 1;
            Bg[t] = *(const h16x8*)(fb + ((size_t)(r1 + dy) * WW + (xb + dx)) * 8);
        }
    } else {
#pragma unroll
        for (int t = 0; t < 3; ++t) {
            int s = t * 4 + gq;
            int dy = s / 3 - 1, dx = s - (s / 3) * 3 - 1;
            int yy = r1 + dy, xx = xb + dx;
            bool ok = (s < 9) && yy >= 0 && yy < HH && xx >= 0 && xx < WW;
            int yc = yy < 0 ? 0 : (yy > HH - 1 ? HH - 1 : yy);
            int xc = xx < 0 ? 0 : (xx > WW - 1 ? WW - 1 : xx);
            h16x8 v = *(const h16x8*)(fb + ((size_t)yc * WW + xc) * 8);
            Bg[t] = ok ? v : z;
        }
    }
}

__global__ __launch_bounds__(1024) void k_cnn_fused(const _Float16* __restrict__ feats,
                                                    const _Float16* __restrict__ wf1,
                                                    const _Float16* __restrict__ wf2,
                                                    const float* __restrict__ b1,
                                                    const float* __restrict__ b2,
                                                    const float* __restrict__ W3,
                                                    const float* __restrict__ b3,
                                                    const float* __restrict__ tg,
                                                    float* __restrict__ out) {
    __shared__ _Float16 h1s[3][512 * 32];    // 98304 B
    __shared__ _Float16 h2s[3][512 * 16];    // 49152 B
    __shared__ h16x2 w3s[72];                // 288 B
    __shared__ float sB[48];                 // b1(32) + b2(16)
    __shared__ float w3b;

    int tid = threadIdx.x;
    int lane = tid & 63, wave = tid >> 6;
    int j = lane & 15, gq = lane >> 4;
    int b = blockIdx.y;
    int y0 = blockIdx.x * TROWS;
    const _Float16* fb = feats + (size_t)b * HW * 8;
    const float* tgb = tg + (size_t)b * HW;
    float* outb = out + (size_t)b * HW;

    const h16x8* wf1v = (const h16x8*)wf1;
    const h16x8* wf2v = (const h16x8*)wf2;
    h16x8 wA1[2][3], wA2[9];
#pragma unroll
    for (int cg = 0; cg < 2; ++cg)
#pragma unroll
        for (int t = 0; t < 3; ++t) wA1[cg][t] = wf1v[(cg * 3 + t) * 64 + lane];
#pragma unroll
    for (int s = 0; s < 9; ++s) wA2[s] = wf2v[s * 64 + lane];
    if (tid < 72) {
        int s = tid >> 3, u = tid & 7;
        h16x2 w;
        w[0] = (_Float16)W3[(2 * u) * 9 + s];
        w[1] = (_Float16)W3[(2 * u + 1) * 9 + s];
        w3s[tid] = w;
    } else if (tid < 105) {
        int q = tid - 72;
        if (q < 32) sB[q] = b1[q];
        else sB[q] = b2[q - 32];
    } else if (tid == 105) w3b = b3[0];
    __syncthreads();

    int g0 = wave * 2;
    const h16x8 z16 = {0,0,0,0,0,0,0,0};
    h16x8 Bv[2][3];
    float accN = 0.f, accC = 0.f;    // conv3 running partials

    for (int i = 0; i < TROWS + 5; ++i) {
        int r1 = y0 + i - 2;              // h1 row computed this iter
        int r2 = y0 + i - 4;              // h2 row computed this iter
        bool do_h1 = (i <= TROWS + 3);
        bool do_h2 = (i >= 3);
        bool h1zero = (r1 < 0) || (r1 > 511);

        // ---- P1a: issue feats global loads for h1 row r1 ----
        if (do_h1 && !h1zero) {
#pragma unroll
            for (int k = 0; k < 2; ++k)
                load_b1(fb, r1, g0 + k, j, gq, Bv[k]);
        }

        // ---- P1b: conv2 -> h2 row r2 (reads h1 rows r2-1..r2+1) ----
        if (do_h2) {
            _Float16* h2row = h2s[s3(r2)];
            if (r2 < 0 || r2 > 511) {
                ((i32x4*)h2row)[tid] = (i32x4){0,0,0,0};
            } else {
                const _Float16* hr[3] = { h1s[s3(r2 - 1)], h1s[s3(r2)], h1s[s3(r2 + 1)] };
                f32x4 b2v = *(const f32x4*)(sB + 32 + gq * 4);
#pragma unroll
                for (int k = 0; k < 2; ++k) {
                    int g = g0 + k;
                    f32x4 acc = {0.f, 0.f, 0.f, 0.f};
#pragma unroll
                    for (int dy = 0; dy < 3; ++dy) {
                        const _Float16* hrow = hr[dy];
#pragma unroll
                        for (int dx = 0; dx < 3; ++dx) {
                            int lpx = g * 16 + j + dx - 1;
                            int lpc = lpx < 0 ? 0 : (lpx > 511 ? 511 : lpx);
                            h16x8 v = ld_h1(hrow, lpc, gq);
                            v = (lpx == lpc) ? v : z16;
                            acc = __builtin_amdgcn_mfma_f32_16x16x32_f16(wA2[dy * 3 + dx], v, acc, 0, 0, 0);
                        }
                    }
                    h16x4 o;
#pragma unroll
                    for (int r = 0; r < 4; ++r) o[r] = (_Float16)fmaxf(acc[r] + b2v[r], 0.f);
                    st_h2(h2row, g * 16 + j, gq, o);
                }
            }
        }
        __syncthreads();

        // ---- P2a: conv1 MFMA + store h1 row r1 ----
        if (do_h1) {
            _Float16* h1row = h1s[s3(r1)];
            if (h1zero) {
                ((i32x4*)h1row)[tid] = (i32x4){0,0,0,0};
                ((i32x4*)h1row)[tid + 1024] = (i32x4){0,0,0,0};
            } else {
#pragma unroll
                for (int k = 0; k < 2; ++k) {
                    f32x4 a1[2] = {};
#pragma unroll
                    for (int t = 0; t < 3; ++t)
#pragma unroll
                        for (int cg = 0; cg < 2; ++cg)
                            a1[cg] = __builtin_amdgcn_mfma_f32_16x16x32_f16(wA1[cg][t], Bv[k][t], a1[cg], 0, 0, 0);
                    int lp = (g0 + k) * 16 + j;
#pragma unroll
                    for (int cg = 0; cg < 2; ++cg) {
                        f32x4 bv = *(const f32x4*)(sB + cg * 16 + gq * 4);
                        h16x4 o;
#pragma unroll
                        for (int r = 0; r < 4; ++r) o[r] = (_Float16)fmaxf(a1[cg][r] + bv[r], 0.f);
                        st_h1(h1row, lp, cg * 4 + gq, o);
                    }
                }
            }
        }

        // ---- P2b: conv3 row-process with running partials ----
        if (do_h2 && tid < 512) {
            int px = tid;
            float d0 = 0.f, d1 = 0.f, d2 = 0.f;
            if (r2 >= 0 && r2 <= 511) {
                const _Float16* hrow = h2s[s3(r2)];
                h16x8 lo[3], hi[3];
#pragma unroll
                for (int dxi = 0; dxi < 3; ++dxi) {
                    int xp = px + dxi - 1;
                    int xc = xp < 0 ? 0 : (xp > 511 ? 511 : xp);
                    int sp0 = (xc >> 2) & 1;
                    h16x8 l = *(const h16x8*)(hrow + xc * 16 + sp0 * 8);
                    h16x8 h = *(const h16x8*)(hrow + xc * 16 + (1 - sp0) * 8);
                    bool ok = (xp == xc);
                    lo[dxi] = ok ? l : z16;
                    hi[dxi] = ok ? h : z16;
                }
#pragma unroll
                for (int kk = 0; kk < 3; ++kk) {
                    float dk = 0.f;
#pragma unroll
                    for (int dxi = 0; dxi < 3; ++dxi) {
                        int s = kk * 3 + dxi;
#pragma unroll
                        for (int q = 0; q < 4; ++q) {
                            h16x2 pl = { lo[dxi][2 * q], lo[dxi][2 * q + 1] };
                            dk = __builtin_amdgcn_fdot2(pl, w3s[s * 8 + q], dk, false);
                        }
#pragma unroll
                        for (int q = 0; q < 4; ++q) {
                            h16x2 ph = { hi[dxi][2 * q], hi[dxi][2 * q + 1] };
                            dk = __builtin_amdgcn_fdot2(ph, w3s[s * 8 + 4 + q], dk, false);
                        }
                    }
                    if (kk == 0) d0 = dk; else if (kk == 1) d1 = dk; else d2 = dk;
                }
            }
            if (i >= 5) {
                float acc = accC + d2 + w3b;
                float sg = 1.f / (1.f + expf(-acc));
                int o = (r2 - 1) * WW + px;
                float tf = 0.7f * tgb[o] + 0.3f * sg;
                outb[o] = fminf(fmaxf(tf, 0.f), 1.f);
            }
            accC = accN + d1;
            accN = d0;
        }
        __syncthreads();
    }
}

extern "C" void kernel_launch(void* const* d_in, const int* in_sizes, int n_in,
                              void* d_out, int out_size, void* d_ws, size_t ws_size,
                              hipStream_t stream) {
    const float* I    = (const float*)d_in[0];
    const float* t0   = (const float*)d_in[1];
    const float* dark = (const float*)d_in[2];
    const float* A    = (const float*)d_in[3];
    const float* W1   = (const float*)d_in[4];
    const float* b1   = (const float*)d_in[5];
    const float* W2   = (const float*)d_in[6];
    const float* b2   = (const float*)d_in[7];
    const float* W3   = (const float*)d_in[8];
    const float* b3   = (const float*)d_in[9];
    float* out = (float*)d_out;
    float* ws  = (float*)d_ws;

    const size_t P = (size_t)BB * HW;       // 2M floats = 8 MB
    float* tg       = ws;                    // [0,P)   fp32
    _Float16* feats = (_Float16*)(ws + P);   // [P,5P)  fp16 [B][HW][8]
    float* g        = ws + 5 * P;            // [5P,6P)
    f32x4* hq       = (f32x4*)(ws + 6 * P);  // [6P,10P)
    f32x2* ab       = (f32x2*)(ws + 10 * P); // [10P,12P)
    f32x2* hab      = (f32x2*)(ws + 12 * P); // [12P,14P)
    _Float16* wf1   = (_Float16*)(ws + 14 * P);  // 3072 halves
    _Float16* wf2   = wf1 + 6 * 64 * 8;          // 4608 halves

    k_wprep<<<1, 64, 0, stream>>>(W1, W2, wf1, wf2);
    k_gray_hbox4<<<BB * HH, 256, 0, stream>>>(I, t0, dark, A, g, hq, feats);
    dim3 gv(WW / 256, BB, HH / SEG);
    k_vbox4_ab<<<gv, 256, 0, stream>>>(hq, ab);
    k_hbox2<<<BB * HH, 256, 0, stream>>>(ab, hab);
    k_vbox2_tg<<<gv, 256, 0, stream>>>(hab, g, tg, feats);

    dim3 gf(HH / TROWS, BB);                // 32 y-tiles x 8 batches = 256 blocks
    k_cnn_fused<<<gf, 1024, 0, stream>>>(feats, wf1, wf2, b1, b2, W3, b3, tg, out);
}

// Round 8
// 231.039 us; speedup vs baseline: 2.2479x; 1.7833x over previous
//
#include <hip/hip_runtime.h>
#include <cmath>

#define BB 8
#define HH 512
#define WW 512
#define HW (HH*WW)
#define RAD 15
#define SEG 32
#define EPS 0.001f
#define INV_K (1.0f/31.0f)
#define TROWS 16
#define NPX 272            // computed px per block: 256 out + 16 halo
#define XOFF (-8)

typedef _Float16 h16x8 __attribute__((ext_vector_type(8)));
typedef _Float16 h16x4 __attribute__((ext_vector_type(4)));
typedef _Float16 h16x2 __attribute__((ext_vector_type(2)));
typedef float f32x4 __attribute__((ext_vector_type(4)));
typedef float f32x2 __attribute__((ext_vector_type(2)));
typedef int   i32x4 __attribute__((ext_vector_type(4)));

static __device__ inline int s3(int r) { return (r + 6) % 3; }   // r >= -6

// ---------------- weight fragment prepack (1 wave) ----------------
__global__ __launch_bounds__(64) void k_wprep(const float* __restrict__ W1,
                                              const float* __restrict__ W2,
                                              _Float16* __restrict__ wf1,
                                              _Float16* __restrict__ wf2) {
    int lane = threadIdx.x;
    int j = lane & 15, g = lane >> 4;
#pragma unroll
    for (int cg = 0; cg < 2; ++cg)
#pragma unroll
        for (int t = 0; t < 3; ++t) {
            int s = t * 4 + g;
            h16x8 w;
#pragma unroll
            for (int i = 0; i < 8; ++i)
                w[i] = (s < 9) ? (_Float16)W1[(cg * 16 + j) * 72 + i * 9 + s] : (_Float16)0.f;
            *(h16x8*)(wf1 + ((cg * 3 + t) * 64 + lane) * 8) = w;
        }
    int ci0 = g * 8;
#pragma unroll
    for (int s = 0; s < 9; ++s) {
        h16x8 w;
#pragma unroll
        for (int i = 0; i < 8; ++i)
            w[i] = (_Float16)W2[j * 288 + (ci0 + i) * 9 + s];
        *(h16x8*)(wf2 + (s * 64 + lane) * 8) = w;
    }
}

// ------- gray + horizontal box + feats(ch0-2,4-7) fp16 -------
__global__ __launch_bounds__(256) void k_gray_hbox4(const float* __restrict__ I,
                                                    const float* __restrict__ p,
                                                    const float* __restrict__ dark,
                                                    const float* __restrict__ A,
                                                    float* __restrict__ g,
                                                    f32x4* __restrict__ hq,
                                                    _Float16* __restrict__ feats) {
    __shared__ float sg[WW], sp[WW];
    int row = blockIdx.x;            // b*HH + y
    int b = row >> 9;
    int base = row * WW;
    const float* Ib = I + (size_t)b * 3 * HW + (size_t)(row & 511) * WW;
    const float* db = dark + (size_t)base;
    _Float16 A0 = (_Float16)A[b * 3 + 0], A1 = (_Float16)A[b * 3 + 1], A2 = (_Float16)A[b * 3 + 2];
    int tid = threadIdx.x;
    for (int x = tid; x < WW; x += 256) {
        float i0 = Ib[x], i1 = Ib[HW + x], i2 = Ib[2 * HW + x];
        float gv = 0.299f * i0 + 0.587f * i1 + 0.114f * i2;
        sg[x] = gv; sp[x] = p[base + x];
        g[base + x] = gv;
        h16x8 v;
        v[0] = (_Float16)i0; v[1] = (_Float16)i1; v[2] = (_Float16)i2;
        v[3] = (_Float16)0.f;           // tg written later by k_vbox2_tg
        v[4] = (_Float16)db[x];
        v[5] = A0; v[6] = A1; v[7] = A2;
        *(h16x8*)(feats + ((size_t)base + x) * 8) = v;
    }
    __syncthreads();
    for (int x = tid; x < WW; x += 256) {
        float s0 = 0.f, s1 = 0.f, s2 = 0.f, s3v = 0.f;
        int lo = x - RAD < 0 ? 0 : x - RAD;
        int hi = x + RAD >= WW ? WW - 1 : x + RAD;
        for (int i = lo; i <= hi; ++i) {
            float gv = sg[i], pv = sp[i];
            s0 += gv; s1 += pv; s2 += gv * pv; s3v += gv * gv;
        }
        f32x4 o = { s0 * INV_K, s1 * INV_K, s2 * INV_K, s3v * INV_K };
        hq[base + x] = o;
    }
}

// ---------------- vertical box of hq, fused a/b ----------------
__global__ __launch_bounds__(256) void k_vbox4_ab(const f32x4* __restrict__ hq,
                                                  f32x2* __restrict__ ab) {
    int x = blockIdx.x * 256 + threadIdx.x;
    int b = blockIdx.y;
    int y0 = blockIdx.z * SEG;
    int pbase = b * HW + x;
    f32x4 s = { 0.f, 0.f, 0.f, 0.f };
    int r0 = y0 - RAD < 0 ? 0 : y0 - RAD;
    for (int r = r0; r < y0 + RAD; ++r) s += hq[pbase + r * WW];
    for (int y = y0; y < y0 + SEG; ++y) {
        if (y + RAD < HH) s += hq[pbase + (y + RAD) * WW];
        float mI = s[0] * INV_K, mP = s[1] * INV_K, mIp = s[2] * INV_K, mII = s[3] * INV_K;
        float cov = mIp - mI * mP;
        float var = mII - mI * mI;
        float av = cov / (var + EPS);
        float bv = mP - av * mI;
        f32x2 o = { av, bv };
        ab[pbase + y * WW] = o;
        if (y - RAD >= 0) s -= hq[pbase + (y - RAD) * WW];
    }
}

// ---------------- horizontal box of ab ----------------
__global__ __launch_bounds__(256) void k_hbox2(const f32x2* __restrict__ ab,
                                               f32x2* __restrict__ hab) {
    __shared__ float sa[WW], sb[WW];
    int base = blockIdx.x * WW;
    int tid = threadIdx.x;
    for (int x = tid; x < WW; x += 256) {
        f32x2 v = ab[base + x];
        sa[x] = v[0]; sb[x] = v[1];
    }
    __syncthreads();
    for (int x = tid; x < WW; x += 256) {
        float s0 = 0.f, s1 = 0.f;
        int lo = x - RAD < 0 ? 0 : x - RAD;
        int hi = x + RAD >= WW ? WW - 1 : x + RAD;
        for (int i = lo; i <= hi; ++i) { s0 += sa[i]; s1 += sb[i]; }
        f32x2 o = { s0 * INV_K, s1 * INV_K };
        hab[base + x] = o;
    }
}

// ------- vertical box of hab + t_guided -> tg fp32 + feats ch3 fp16 -------
__global__ __launch_bounds__(256) void k_vbox2_tg(const f32x2* __restrict__ hab,
                                                  const float* __restrict__ g,
                                                  float* __restrict__ tg,
                                                  _Float16* __restrict__ feats) {
    int x = blockIdx.x * 256 + threadIdx.x;
    int b = blockIdx.y;
    int y0 = blockIdx.z * SEG;
    int pbase = b * HW + x;
    f32x2 s = { 0.f, 0.f };
    int r0 = y0 - RAD < 0 ? 0 : y0 - RAD;
    for (int r = r0; r < y0 + RAD; ++r) s += hab[pbase + r * WW];
    for (int y = y0; y < y0 + SEG; ++y) {
        if (y + RAD < HH) s += hab[pbase + (y + RAD) * WW];
        int o = pbase + y * WW;
        float val = (s[0] * INV_K) * g[o] + (s[1] * INV_K);
        tg[o] = val;
        feats[(size_t)o * 8 + 3] = (_Float16)val;
        if (y - RAD >= 0) s -= hab[pbase + (y - RAD) * WW];
    }
}

// ---------------- fused conv1+conv2+conv3 ----------------
// h1 LDS row: [NPX px][32 ch] fp16; 16B granule c (=ch/8) at sp = c ^ ((lp>>1)&3)
static __device__ inline h16x8 ld_h1(const _Float16* hrow, int lp, int c) {
    int sp = c ^ ((lp >> 1) & 3);
    return *(const h16x8*)(hrow + lp * 32 + sp * 8);
}
static __device__ inline void st_h1(_Float16* hrow, int lp, int u, h16x4 o) {   // u = ch/4
    int sp = (u >> 1) ^ ((lp >> 1) & 3);
    *(h16x4*)(hrow + lp * 32 + sp * 8 + (u & 1) * 4) = o;
}
// h2 LDS row: [NPX px][16 ch] fp16; granule c at sp = c ^ ((lp>>2)&1)
static __device__ inline void st_h2(_Float16* hrow, int lp, int u, h16x4 o) {   // u = ch/4
    int sp = (u >> 1) ^ ((lp >> 2) & 1);
    *(h16x4*)(hrow + lp * 16 + sp * 8 + (u & 1) * 4) = o;
}

static __device__ inline void load_b1(const _Float16* fb, int r1, int X0, int g,
                                      int j, int gq, h16x8 Bg[3]) {
    const h16x8 z = {0,0,0,0,0,0,0,0};
    bool xedgeG = (X0 == 0 && g == 0) || (X0 == 256 && g == 16);
    int gxb = X0 + XOFF + g * 16 + j;
    if (!xedgeG && r1 >= 1 && r1 <= 509) {
#pragma unroll
        for (int t = 0; t < 3; ++t) {
            int s = t * 4 + gq;
            int dy = s / 3 - 1, dx = s - (s / 3) * 3 - 1;
            Bg[t] = *(const h16x8*)(fb + ((size_t)(r1 + dy) * WW + (gxb + dx)) * 8);
        }
    } else {
#pragma unroll
        for (int t = 0; t < 3; ++t) {
            int s = t * 4 + gq;
            int dy = s / 3 - 1, dx = s - (s / 3) * 3 - 1;
            int yy = r1 + dy, xx = gxb + dx;
            bool ok = (s < 9) && yy >= 0 && yy < HH && xx >= 0 && xx < WW;
            int yc = yy < 0 ? 0 : (yy > HH - 1 ? HH - 1 : yy);
            int xc = xx < 0 ? 0 : (xx > WW - 1 ? WW - 1 : xx);
            h16x8 v = *(const h16x8*)(fb + ((size_t)yc * WW + xc) * 8);
            Bg[t] = ok ? v : z;
        }
    }
}

static __device__ inline f32x4 conv2_group(const _Float16* hr0, const _Float16* hr1,
                                           const _Float16* hr2, const h16x8* wA2,
                                           int g, int j, int gq, int X0) {
    f32x4 acc = {0.f, 0.f, 0.f, 0.f};
    const h16x8 z = {0,0,0,0,0,0,0,0};
    int lpb = g * 16 + j;
    const _Float16* rows[3] = {hr0, hr1, hr2};
    if (g != 0 && g != 16) {
#pragma unroll
        for (int dy = 0; dy < 3; ++dy) {
            const _Float16* hrow = rows[dy];
            h16x8 vm = ld_h1(hrow, lpb - 1, gq);
            h16x8 v0 = ld_h1(hrow, lpb, gq);
            h16x8 vp = ld_h1(hrow, lpb + 1, gq);
            acc = __builtin_amdgcn_mfma_f32_16x16x32_f16(wA2[dy * 3 + 0], vm, acc, 0, 0, 0);
            acc = __builtin_amdgcn_mfma_f32_16x16x32_f16(wA2[dy * 3 + 1], v0, acc, 0, 0, 0);
            acc = __builtin_amdgcn_mfma_f32_16x16x32_f16(wA2[dy * 3 + 2], vp, acc, 0, 0, 0);
        }
    } else {
        // edge groups: out-of-strip lp clamped — corrupt values land only in
        // h2 slots never consumed by conv3 (lp<7 or lp>264); out-of-IMAGE taps zeroed.
#pragma unroll
        for (int dy = 0; dy < 3; ++dy) {
            const _Float16* hrow = rows[dy];
#pragma unroll
            for (int dx = 0; dx < 3; ++dx) {
                int lpx = lpb + dx - 1;
                int gx = X0 + XOFF + lpx;
                bool ok = (gx >= 0) && (gx < WW);
                int lpc = lpx < 0 ? 0 : (lpx > NPX - 1 ? NPX - 1 : lpx);
                h16x8 v = ok ? ld_h1(hrow, lpc, gq) : z;
                acc = __builtin_amdgcn_mfma_f32_16x16x32_f16(wA2[dy * 3 + dx], v, acc, 0, 0, 0);
            }
        }
    }
    return acc;
}

__global__ __launch_bounds__(512, 2) void k_cnn_fused(const _Float16* __restrict__ feats,
                                                      const _Float16* __restrict__ wf1,
                                                      const _Float16* __restrict__ wf2,
                                                      const float* __restrict__ b1,
                                                      const float* __restrict__ b2,
                                                      const float* __restrict__ W3,
                                                      const float* __restrict__ b3,
                                                      const float* __restrict__ tg,
                                                      float* __restrict__ out) {
    __shared__ _Float16 h1s[3][NPX * 32];    // 52,224 B
    __shared__ _Float16 h2s[3][NPX * 16];    // 26,112 B
    __shared__ h16x2 w3s[72];
    __shared__ float w3bias;

    int tid = threadIdx.x;
    int lane = tid & 63, wave = tid >> 6;
    int j = lane & 15, gq = lane >> 4;
    int b = blockIdx.y;
    int X0 = (blockIdx.x & 1) * 256;
    int y0 = (blockIdx.x >> 1) * TROWS;
    const _Float16* fb = feats + (size_t)b * HW * 8;
    const float* tgb = tg + (size_t)b * HW;
    float* outb = out + (size_t)b * HW;

    const h16x8* wf1v = (const h16x8*)wf1;
    const h16x8* wf2v = (const h16x8*)wf2;
    h16x8 wA1[2][3], wA2[9];
#pragma unroll
    for (int cg = 0; cg < 2; ++cg)
#pragma unroll
        for (int t = 0; t < 3; ++t) wA1[cg][t] = wf1v[(cg * 3 + t) * 64 + lane];
#pragma unroll
    for (int s = 0; s < 9; ++s) wA2[s] = wf2v[s * 64 + lane];
    f32x4 bias1[2];
    bias1[0] = *(const f32x4*)(b1 + gq * 4);
    bias1[1] = *(const f32x4*)(b1 + 16 + gq * 4);
    f32x4 bias2 = *(const f32x4*)(b2 + gq * 4);
    if (tid < 72) {
        int s = tid >> 3, u = tid & 7;
        h16x2 w;
        w[0] = (_Float16)W3[(2 * u) * 9 + s];
        w[1] = (_Float16)W3[(2 * u + 1) * 9 + s];
        w3s[tid] = w;
    }
    if (tid == 72) w3bias = b3[0];
    __syncthreads();

    int g0 = wave * 2;
    const h16x8 z16 = {0,0,0,0,0,0,0,0};
    h16x8 Bv[2][3];      // prefetched conv1 B-frags, groups {wave*2, wave*2+1}
    h16x8 Bg16[3];       // group 16 (wave 0 only)
    const i32x4 zz = {0, 0, 0, 0};
    float accN = 0.f, accC = 0.f;    // conv3 running partials

    for (int i = 0; i < TROWS + 5; ++i) {
        int r1 = y0 + i - 2;              // h1 row computed this iter
        int r2 = y0 + i - 4;              // h2 row computed this iter
        bool do_h1 = (i <= TROWS + 3);
        bool do_h2 = (i >= 3);
        bool h1zero = (r1 < 0) || (r1 > 511);

        // ---- P1a: issue feats global loads for h1 row r1 (prefetch) ----
        if (do_h1 && !h1zero) {
#pragma unroll
            for (int k = 0; k < 2; ++k)
                load_b1(fb, r1, X0, g0 + k, j, gq, Bv[k]);
            if (wave == 0) load_b1(fb, r1, X0, 16, j, gq, Bg16);
        }

        // ---- P1b: conv2 -> h2 row r2 (reads h1 rows r2-1..r2+1 from LDS) ----
        if (do_h2) {
            _Float16* h2row = h2s[s3(r2)];
            if (r2 < 0 || r2 > 511) {
                for (int q = tid; q < 544; q += 512) ((i32x4*)h2row)[q] = zz;
            } else {
                const _Float16* hr0 = h1s[s3(r2 - 1)];
                const _Float16* hr1 = h1s[s3(r2)];
                const _Float16* hr2 = h1s[s3(r2 + 1)];
#pragma unroll
                for (int k = 0; k < 2; ++k) {
                    int g = g0 + k;
                    f32x4 a2 = conv2_group(hr0, hr1, hr2, wA2, g, j, gq, X0);
                    h16x4 o;
#pragma unroll
                    for (int r = 0; r < 4; ++r) o[r] = (_Float16)fmaxf(a2[r] + bias2[r], 0.f);
                    st_h2(h2row, g * 16 + j, gq, o);
                }
                if (wave == 0) {
                    f32x4 a2 = conv2_group(hr0, hr1, hr2, wA2, 16, j, gq, X0);
                    h16x4 o;
#pragma unroll
                    for (int r = 0; r < 4; ++r) o[r] = (_Float16)fmaxf(a2[r] + bias2[r], 0.f);
                    st_h2(h2row, 16 * 16 + j, gq, o);
                }
            }
        }
        __syncthreads();

        // ---- P2a: conv1 MFMA + store h1 row r1 ----
        if (do_h1) {
            _Float16* h1row = h1s[s3(r1)];
            if (h1zero) {
                for (int q = tid; q < 1088; q += 512) ((i32x4*)h1row)[q] = zz;
            } else {
#pragma unroll
                for (int k = 0; k < 2; ++k) {
                    f32x4 a1[2] = {};
#pragma unroll
                    for (int t = 0; t < 3; ++t)
#pragma unroll
                        for (int cg = 0; cg < 2; ++cg)
                            a1[cg] = __builtin_amdgcn_mfma_f32_16x16x32_f16(wA1[cg][t], Bv[k][t], a1[cg], 0, 0, 0);
                    int lp = (g0 + k) * 16 + j;
#pragma unroll
                    for (int cg = 0; cg < 2; ++cg) {
                        h16x4 o;
#pragma unroll
                        for (int r = 0; r < 4; ++r) o[r] = (_Float16)fmaxf(a1[cg][r] + bias1[cg][r], 0.f);
                        st_h1(h1row, lp, cg * 4 + gq, o);
                    }
                }
                if (wave == 0) {
                    f32x4 a1[2] = {};
#pragma unroll
                    for (int t = 0; t < 3; ++t)
#pragma unroll
                        for (int cg = 0; cg < 2; ++cg)
                            a1[cg] = __builtin_amdgcn_mfma_f32_16x16x32_f16(wA1[cg][t], Bg16[t], a1[cg], 0, 0, 0);
                    int lp = 16 * 16 + j;
#pragma unroll
                    for (int cg = 0; cg < 2; ++cg) {
                        h16x4 o;
#pragma unroll
                        for (int r = 0; r < 4; ++r) o[r] = (_Float16)fmaxf(a1[cg][r] + bias1[cg][r], 0.f);
                        st_h1(h1row, lp, cg * 4 + gq, o);
                    }
                }
            }
        }

        // ---- P2b: conv3 row-process with running partials (h2 row r2 read once) ----
        if (do_h2 && tid < 256) {
            float d0 = 0.f, d1 = 0.f, d2 = 0.f;
            if (r2 >= 0 && r2 <= 511) {
                const _Float16* hrow = h2s[s3(r2)];
#pragma unroll
                for (int dxi = 0; dxi < 3; ++dxi) {
                    int xim = X0 + tid + dxi - 1;
                    if (xim >= 0 && xim < WW) {
                        int lpx = tid + 8 + dxi - 1;
                        int sp0 = (lpx >> 2) & 1;
                        h16x8 lo = *(const h16x8*)(hrow + lpx * 16 + sp0 * 8);
                        h16x8 hi = *(const h16x8*)(hrow + lpx * 16 + (1 - sp0) * 8);
#pragma unroll
                        for (int q = 0; q < 4; ++q) {
                            h16x2 pl = { lo[2 * q], lo[2 * q + 1] };
                            d0 = __builtin_amdgcn_fdot2(pl, w3s[(0 + dxi) * 8 + q], d0, false);
                            d1 = __builtin_amdgcn_fdot2(pl, w3s[(3 + dxi) * 8 + q], d1, false);
                            d2 = __builtin_amdgcn_fdot2(pl, w3s[(6 + dxi) * 8 + q], d2, false);
                        }
#pragma unroll
                        for (int q = 0; q < 4; ++q) {
                            h16x2 ph = { hi[2 * q], hi[2 * q + 1] };
                            d0 = __builtin_amdgcn_fdot2(ph, w3s[(0 + dxi) * 8 + 4 + q], d0, false);
                            d1 = __builtin_amdgcn_fdot2(ph, w3s[(3 + dxi) * 8 + 4 + q], d1, false);
                            d2 = __builtin_amdgcn_fdot2(ph, w3s[(6 + dxi) * 8 + 4 + q], d2, false);
                        }
                    }
                }
            }
            if (i >= 5) {
                float acc = accC + d2 + w3bias;
                float sg = 1.f / (1.f + expf(-acc));
                int o = (r2 - 1) * WW + X0 + tid;
                float tf = 0.7f * tgb[o] + 0.3f * sg;
                outb[o] = fminf(fmaxf(tf, 0.f), 1.f);
            }
            accC = accN + d1;
            accN = d0;
        }
        __syncthreads();
    }
}

extern "C" void kernel_launch(void* const* d_in, const int* in_sizes, int n_in,
                              void* d_out, int out_size, void* d_ws, size_t ws_size,
                              hipStream_t stream) {
    const float* I    = (const float*)d_in[0];
    const float* t0   = (const float*)d_in[1];
    const float* dark = (const float*)d_in[2];
    const float* A    = (const float*)d_in[3];
    const float* W1   = (const float*)d_in[4];
    const float* b1   = (const float*)d_in[5];
    const float* W2   = (const float*)d_in[6];
    const float* b2   = (const float*)d_in[7];
    const float* W3   = (const float*)d_in[8];
    const float* b3   = (const float*)d_in[9];
    float* out = (float*)d_out;
    float* ws  = (float*)d_ws;

    const size_t P = (size_t)BB * HW;       // 2M floats = 8 MB
    float* tg       = ws;                    // [0,P)   fp32
    _Float16* feats = (_Float16*)(ws + P);   // [P,5P)  fp16 [B][HW][8]
    float* g        = ws + 5 * P;            // [5P,6P)
    f32x4* hq       = (f32x4*)(ws + 6 * P);  // [6P,10P)
    f32x2* ab       = (f32x2*)(ws + 10 * P); // [10P,12P)
    f32x2* hab      = (f32x2*)(ws + 12 * P); // [12P,14P)
    _Float16* wf1   = (_Float16*)(ws + 14 * P);  // 3072 halves
    _Float16* wf2   = wf1 + 6 * 64 * 8;          // 4608 halves

    k_wprep<<<1, 64, 0, stream>>>(W1, W2, wf1, wf2);
    k_gray_hbox4<<<BB * HH, 256, 0, stream>>>(I, t0, dark, A, g, hq, feats);
    dim3 gv(WW / 256, BB, HH / SEG);
    k_vbox4_ab<<<gv, 256, 0, stream>>>(hq, ab);
    k_hbox2<<<BB * HH, 256, 0, stream>>>(ab, hab);
    k_vbox2_tg<<<gv, 256, 0, stream>>>(hab, g, tg, feats);

    dim3 gf(64, BB);                        // 32 y-tiles x 2 x-halves x 8 batches
    k_cnn_fused<<<gf, 512, 0, stream>>>(feats, wf1, wf2, b1, b2, W3, b3, tg, out);
}

// Round 9
// 222.987 us; speedup vs baseline: 2.3290x; 1.0361x over previous
//
#include <hip/hip_runtime.h>
#include <cmath>

#define BB 8
#define HH 512
#define WW 512
#define HW (HH*WW)
#define RAD 15
#define SEG 32
#define EPS 0.001f
#define INV_K (1.0f/31.0f)
#define TROWS 16
#define NPX 272            // computed px per block: 256 out + 16 halo
#define XOFF (-8)

typedef _Float16 h16x8 __attribute__((ext_vector_type(8)));
typedef _Float16 h16x4 __attribute__((ext_vector_type(4)));
typedef _Float16 h16x2 __attribute__((ext_vector_type(2)));
typedef float f32x4 __attribute__((ext_vector_type(4)));
typedef float f32x2 __attribute__((ext_vector_type(2)));
typedef int   i32x4 __attribute__((ext_vector_type(4)));

static __device__ inline int s3(int r) { return (r + 6) % 3; }   // r >= -6

// ---------------- weight fragment prepack (1 wave) ----------------
__global__ __launch_bounds__(64) void k_wprep(const float* __restrict__ W1,
                                              const float* __restrict__ W2,
                                              _Float16* __restrict__ wf1,
                                              _Float16* __restrict__ wf2) {
    int lane = threadIdx.x;
    int j = lane & 15, g = lane >> 4;
#pragma unroll
    for (int cg = 0; cg < 2; ++cg)
#pragma unroll
        for (int t = 0; t < 3; ++t) {
            int s = t * 4 + g;
            h16x8 w;
#pragma unroll
            for (int i = 0; i < 8; ++i)
                w[i] = (s < 9) ? (_Float16)W1[(cg * 16 + j) * 72 + i * 9 + s] : (_Float16)0.f;
            *(h16x8*)(wf1 + ((cg * 3 + t) * 64 + lane) * 8) = w;
        }
    int ci0 = g * 8;
#pragma unroll
    for (int s = 0; s < 9; ++s) {
        h16x8 w;
#pragma unroll
        for (int i = 0; i < 8; ++i)
            w[i] = (_Float16)W2[j * 288 + (ci0 + i) * 9 + s];
        *(h16x8*)(wf2 + (s * 64 + lane) * 8) = w;
    }
}

// ------- gray + horizontal box + feats(ch0-2,4-7) fp16 -------
__global__ __launch_bounds__(256) void k_gray_hbox4(const float* __restrict__ I,
                                                    const float* __restrict__ p,
                                                    const float* __restrict__ dark,
                                                    const float* __restrict__ A,
                                                    float* __restrict__ g,
                                                    f32x4* __restrict__ hq,
                                                    _Float16* __restrict__ feats) {
    __shared__ float sg[WW], sp[WW];
    int row = blockIdx.x;            // b*HH + y
    int b = row >> 9;
    int base = row * WW;
    const float* Ib = I + (size_t)b * 3 * HW + (size_t)(row & 511) * WW;
    const float* db = dark + (size_t)base;
    _Float16 A0 = (_Float16)A[b * 3 + 0], A1 = (_Float16)A[b * 3 + 1], A2 = (_Float16)A[b * 3 + 2];
    int tid = threadIdx.x;
    for (int x = tid; x < WW; x += 256) {
        float i0 = Ib[x], i1 = Ib[HW + x], i2 = Ib[2 * HW + x];
        float gv = 0.299f * i0 + 0.587f * i1 + 0.114f * i2;
        sg[x] = gv; sp[x] = p[base + x];
        g[base + x] = gv;
        h16x8 v;
        v[0] = (_Float16)i0; v[1] = (_Float16)i1; v[2] = (_Float16)i2;
        v[3] = (_Float16)0.f;           // tg written later by k_vbox2_tg
        v[4] = (_Float16)db[x];
        v[5] = A0; v[6] = A1; v[7] = A2;
        *(h16x8*)(feats + ((size_t)base + x) * 8) = v;
    }
    __syncthreads();
    for (int x = tid; x < WW; x += 256) {
        float s0 = 0.f, s1 = 0.f, s2 = 0.f, s3v = 0.f;
        int lo = x - RAD < 0 ? 0 : x - RAD;
        int hi = x + RAD >= WW ? WW - 1 : x + RAD;
        for (int i = lo; i <= hi; ++i) {
            float gv = sg[i], pv = sp[i];
            s0 += gv; s1 += pv; s2 += gv * pv; s3v += gv * gv;
        }
        f32x4 o = { s0 * INV_K, s1 * INV_K, s2 * INV_K, s3v * INV_K };
        hq[base + x] = o;
    }
}

// ---------------- vertical box of hq, fused a/b ----------------
__global__ __launch_bounds__(256) void k_vbox4_ab(const f32x4* __restrict__ hq,
                                                  f32x2* __restrict__ ab) {
    int x = blockIdx.x * 256 + threadIdx.x;
    int b = blockIdx.y;
    int y0 = blockIdx.z * SEG;
    int pbase = b * HW + x;
    f32x4 s = { 0.f, 0.f, 0.f, 0.f };
    int r0 = y0 - RAD < 0 ? 0 : y0 - RAD;
    for (int r = r0; r < y0 + RAD; ++r) s += hq[pbase + r * WW];
    for (int y = y0; y < y0 + SEG; ++y) {
        if (y + RAD < HH) s += hq[pbase + (y + RAD) * WW];
        float mI = s[0] * INV_K, mP = s[1] * INV_K, mIp = s[2] * INV_K, mII = s[3] * INV_K;
        float cov = mIp - mI * mP;
        float var = mII - mI * mI;
        float av = cov / (var + EPS);
        float bv = mP - av * mI;
        f32x2 o = { av, bv };
        ab[pbase + y * WW] = o;
        if (y - RAD >= 0) s -= hq[pbase + (y - RAD) * WW];
    }
}

// ---------------- horizontal box of ab ----------------
__global__ __launch_bounds__(256) void k_hbox2(const f32x2* __restrict__ ab,
                                               f32x2* __restrict__ hab) {
    __shared__ float sa[WW], sb[WW];
    int base = blockIdx.x * WW;
    int tid = threadIdx.x;
    for (int x = tid; x < WW; x += 256) {
        f32x2 v = ab[base + x];
        sa[x] = v[0]; sb[x] = v[1];
    }
    __syncthreads();
    for (int x = tid; x < WW; x += 256) {
        float s0 = 0.f, s1 = 0.f;
        int lo = x - RAD < 0 ? 0 : x - RAD;
        int hi = x + RAD >= WW ? WW - 1 : x + RAD;
        for (int i = lo; i <= hi; ++i) { s0 += sa[i]; s1 += sb[i]; }
        f32x2 o = { s0 * INV_K, s1 * INV_K };
        hab[base + x] = o;
    }
}

// ------- vertical box of hab + t_guided -> tg fp32 + feats ch3 fp16 -------
__global__ __launch_bounds__(256) void k_vbox2_tg(const f32x2* __restrict__ hab,
                                                  const float* __restrict__ g,
                                                  float* __restrict__ tg,
                                                  _Float16* __restrict__ feats) {
    int x = blockIdx.x * 256 + threadIdx.x;
    int b = blockIdx.y;
    int y0 = blockIdx.z * SEG;
    int pbase = b * HW + x;
    f32x2 s = { 0.f, 0.f };
    int r0 = y0 - RAD < 0 ? 0 : y0 - RAD;
    for (int r = r0; r < y0 + RAD; ++r) s += hab[pbase + r * WW];
    for (int y = y0; y < y0 + SEG; ++y) {
        if (y + RAD < HH) s += hab[pbase + (y + RAD) * WW];
        int o = pbase + y * WW;
        float val = (s[0] * INV_K) * g[o] + (s[1] * INV_K);
        tg[o] = val;
        feats[(size_t)o * 8 + 3] = (_Float16)val;
        if (y - RAD >= 0) s -= hab[pbase + (y - RAD) * WW];
    }
}

// ---------------- fused conv1+conv2+conv3 ----------------
// h1 LDS row: [NPX px][32 ch] fp16; 16B granule c (=ch/8) at sp = c ^ ((lp>>1)&3)
static __device__ inline h16x8 ld_h1(const _Float16* hrow, int lp, int c) {
    int sp = c ^ ((lp >> 1) & 3);
    return *(const h16x8*)(hrow + lp * 32 + sp * 8);
}
static __device__ inline void st_h1(_Float16* hrow, int lp, int u, h16x4 o) {   // u = ch/4
    int sp = (u >> 1) ^ ((lp >> 1) & 3);
    *(h16x4*)(hrow + lp * 32 + sp * 8 + (u & 1) * 4) = o;
}
// h2 LDS row (1-deep): [NPX px][16 ch] fp16; granule c at sp = c ^ ((lp>>2)&1)
static __device__ inline void st_h2(_Float16* hrow, int lp, int u, h16x4 o) {   // u = ch/4
    int sp = (u >> 1) ^ ((lp >> 2) & 1);
    *(h16x4*)(hrow + lp * 16 + sp * 8 + (u & 1) * 4) = o;
}

static __device__ inline void load_b1(const _Float16* fb, int r1, int X0, int g,
                                      int j, int gq, h16x8 Bg[3]) {
    const h16x8 z = {0,0,0,0,0,0,0,0};
    bool xedgeG = (X0 == 0 && g == 0) || (X0 == 256 && g == 16);
    int gxb = X0 + XOFF + g * 16 + j;
    if (!xedgeG && r1 >= 1 && r1 <= 509) {
#pragma unroll
        for (int t = 0; t < 3; ++t) {
            int s = t * 4 + gq;
            int dy = s / 3 - 1, dx = s - (s / 3) * 3 - 1;
            Bg[t] = *(const h16x8*)(fb + ((size_t)(r1 + dy) * WW + (gxb + dx)) * 8);
        }
    } else {
#pragma unroll
        for (int t = 0; t < 3; ++t) {
            int s = t * 4 + gq;
            int dy = s / 3 - 1, dx = s - (s / 3) * 3 - 1;
            int yy = r1 + dy, xx = gxb + dx;
            bool ok = (s < 9) && yy >= 0 && yy < HH && xx >= 0 && xx < WW;
            int yc = yy < 0 ? 0 : (yy > HH - 1 ? HH - 1 : yy);
            int xc = xx < 0 ? 0 : (xx > WW - 1 ? WW - 1 : xx);
            h16x8 v = *(const h16x8*)(fb + ((size_t)yc * WW + xc) * 8);
            Bg[t] = ok ? v : z;
        }
    }
}

// conv2 one group; vdy[k] = row r2-1+k valid (wave-uniform). Invalid rows skipped (zero-pad).
static __device__ inline f32x4 conv2_group(const _Float16* hr0, const _Float16* hr1,
                                           const _Float16* hr2, bool v0y, bool v1y, bool v2y,
                                           const h16x8* wA2, int g, int j, int gq, int X0) {
    f32x4 acc = {0.f, 0.f, 0.f, 0.f};
    const h16x8 z = {0,0,0,0,0,0,0,0};
    int lpb = g * 16 + j;
    const _Float16* rows[3] = {hr0, hr1, hr2};
    bool vy[3] = {v0y, v1y, v2y};
    if (g != 0 && g != 16) {
#pragma unroll
        for (int dy = 0; dy < 3; ++dy) {
            if (vy[dy]) {
                const _Float16* hrow = rows[dy];
                h16x8 vm = ld_h1(hrow, lpb - 1, gq);
                h16x8 v0 = ld_h1(hrow, lpb, gq);
                h16x8 vp = ld_h1(hrow, lpb + 1, gq);
                acc = __builtin_amdgcn_mfma_f32_16x16x32_f16(wA2[dy * 3 + 0], vm, acc, 0, 0, 0);
                acc = __builtin_amdgcn_mfma_f32_16x16x32_f16(wA2[dy * 3 + 1], v0, acc, 0, 0, 0);
                acc = __builtin_amdgcn_mfma_f32_16x16x32_f16(wA2[dy * 3 + 2], vp, acc, 0, 0, 0);
            }
        }
    } else {
        // edge groups: out-of-strip lp clamped — corrupt values land only in
        // h2 slots never consumed by conv3 (lp<7 or lp>264); out-of-IMAGE taps zeroed.
#pragma unroll
        for (int dy = 0; dy < 3; ++dy) {
            if (vy[dy]) {
                const _Float16* hrow = rows[dy];
#pragma unroll
                for (int dx = 0; dx < 3; ++dx) {
                    int lpx = lpb + dx - 1;
                    int gx = X0 + XOFF + lpx;
                    bool ok = (gx >= 0) && (gx < WW);
                    int lpc = lpx < 0 ? 0 : (lpx > NPX - 1 ? NPX - 1 : lpx);
                    h16x8 v = ok ? ld_h1(hrow, lpc, gq) : z;
                    acc = __builtin_amdgcn_mfma_f32_16x16x32_f16(wA2[dy * 3 + dx], v, acc, 0, 0, 0);
                }
            }
        }
    }
    return acc;
}

__global__ __launch_bounds__(512, 2) void k_cnn_fused(const _Float16* __restrict__ feats,
                                                      const _Float16* __restrict__ wf1,
                                                      const _Float16* __restrict__ wf2,
                                                      const float* __restrict__ b1,
                                                      const float* __restrict__ b2,
                                                      const float* __restrict__ W3,
                                                      const float* __restrict__ b3,
                                                      const float* __restrict__ tg,
                                                      float* __restrict__ out) {
    __shared__ _Float16 h1s[3][NPX * 32];    // 52,224 B
    __shared__ _Float16 h2s[NPX * 16];       //  8,704 B (1-deep: conv3 reads only row r2)
    __shared__ h16x2 w3s[72];
    __shared__ float w3bias;

    int tid = threadIdx.x;
    int lane = tid & 63, wave = tid >> 6;
    int j = lane & 15, gq = lane >> 4;
    int b = blockIdx.y;
    int X0 = (blockIdx.x & 1) * 256;
    int y0 = (blockIdx.x >> 1) * TROWS;
    const _Float16* fb = feats + (size_t)b * HW * 8;
    const float* tgb = tg + (size_t)b * HW;
    float* outb = out + (size_t)b * HW;

    const h16x8* wf1v = (const h16x8*)wf1;
    const h16x8* wf2v = (const h16x8*)wf2;
    h16x8 wA1[2][3], wA2[9];
#pragma unroll
    for (int cg = 0; cg < 2; ++cg)
#pragma unroll
        for (int t = 0; t < 3; ++t) wA1[cg][t] = wf1v[(cg * 3 + t) * 64 + lane];
#pragma unroll
    for (int s = 0; s < 9; ++s) wA2[s] = wf2v[s * 64 + lane];
    f32x4 bias1[2];
    bias1[0] = *(const f32x4*)(b1 + gq * 4);
    bias1[1] = *(const f32x4*)(b1 + 16 + gq * 4);
    f32x4 bias2 = *(const f32x4*)(b2 + gq * 4);
    if (tid < 72) {
        int s = tid >> 3, u = tid & 7;
        h16x2 w;
        w[0] = (_Float16)W3[(2 * u) * 9 + s];
        w[1] = (_Float16)W3[(2 * u + 1) * 9 + s];
        w3s[tid] = w;
    }
    if (tid == 72) w3bias = b3[0];
    __syncthreads();

    int g0 = wave * 2;
    h16x8 Bv[2][3];      // prefetched conv1 B-frags, groups {wave*2, wave*2+1}
    h16x8 Bg16[3];       // group 16 (wave 4 only — off the conv3-lead wave)
    // conv3 half-split state: px = tid>>1, half = tid&1 (channels 8h..8h+7)
    int c3px = tid >> 1, c3h = tid & 1;
    float accN = 0.f, accC = 0.f;

    for (int i = 0; i < TROWS + 5; ++i) {
        int r1 = y0 + i - 2;              // h1 row computed this iter
        int r2 = y0 + i - 4;              // h2 row computed this iter
        bool do_h1 = (i <= TROWS + 3) && (r1 >= 0) && (r1 <= 511);
        bool do_h2 = (i >= 3) && (r2 >= 0) && (r2 <= 511);
        bool v0y = (r2 - 1 >= 0), v1y = true, v2y = (r2 + 1 <= 511);

        // ---- P1a: issue feats global loads for h1 row r1 (prefetch) ----
        if (do_h1) {
#pragma unroll
            for (int k = 0; k < 2; ++k)
                load_b1(fb, r1, X0, g0 + k, j, gq, Bv[k]);
            if (wave == 4) load_b1(fb, r1, X0, 16, j, gq, Bg16);
        }

        // ---- P1b: conv2 -> h2 row r2 (reads h1 rows r2-1..r2+1 from LDS) ----
        if (do_h2) {
            const _Float16* hr0 = h1s[s3(r2 - 1)];
            const _Float16* hr1 = h1s[s3(r2)];
            const _Float16* hr2 = h1s[s3(r2 + 1)];
#pragma unroll
            for (int k = 0; k < 2; ++k) {
                int g = g0 + k;
                f32x4 a2 = conv2_group(hr0, hr1, hr2, v0y, v1y, v2y, wA2, g, j, gq, X0);
                h16x4 o;
#pragma unroll
                for (int r = 0; r < 4; ++r) o[r] = (_Float16)fmaxf(a2[r] + bias2[r], 0.f);
                st_h2(h2s, g * 16 + j, gq, o);
            }
            if (wave == 4) {
                f32x4 a2 = conv2_group(hr0, hr1, hr2, v0y, v1y, v2y, wA2, 16, j, gq, X0);
                h16x4 o;
#pragma unroll
                for (int r = 0; r < 4; ++r) o[r] = (_Float16)fmaxf(a2[r] + bias2[r], 0.f);
                st_h2(h2s, 16 * 16 + j, gq, o);
            }
        }
        __syncthreads();

        // ---- P2a: conv1 MFMA + store h1 row r1 ----
        if (do_h1) {
            _Float16* h1row = h1s[s3(r1)];
#pragma unroll
            for (int k = 0; k < 2; ++k) {
                f32x4 a1[2] = {};
#pragma unroll
                for (int t = 0; t < 3; ++t)
#pragma unroll
                    for (int cg = 0; cg < 2; ++cg)
                        a1[cg] = __builtin_amdgcn_mfma_f32_16x16x32_f16(wA1[cg][t], Bv[k][t], a1[cg], 0, 0, 0);
                int lp = (g0 + k) * 16 + j;
#pragma unroll
                for (int cg = 0; cg < 2; ++cg) {
                    h16x4 o;
#pragma unroll
                    for (int r = 0; r < 4; ++r) o[r] = (_Float16)fmaxf(a1[cg][r] + bias1[cg][r], 0.f);
                    st_h1(h1row, lp, cg * 4 + gq, o);
                }
            }
            if (wave == 4) {
                f32x4 a1[2] = {};
#pragma unroll
                for (int t = 0; t < 3; ++t)
#pragma unroll
                    for (int cg = 0; cg < 2; ++cg)
                        a1[cg] = __builtin_amdgcn_mfma_f32_16x16x32_f16(wA1[cg][t], Bg16[t], a1[cg], 0, 0, 0);
                int lp = 16 * 16 + j;
#pragma unroll
                for (int cg = 0; cg < 2; ++cg) {
                    h16x4 o;
#pragma unroll
                    for (int r = 0; r < 4; ++r) o[r] = (_Float16)fmaxf(a1[cg][r] + bias1[cg][r], 0.f);
                    st_h1(h1row, lp, cg * 4 + gq, o);
                }
            }
        }

        // ---- P2b: conv3 (all 512 threads, 8 ch each) + blend + store out row r3 ----
        {
            float d0 = 0.f, d1 = 0.f, d2 = 0.f;
            if (do_h2) {
#pragma unroll
                for (int dx = 0; dx < 3; ++dx) {
                    int xim = X0 + c3px + dx - 1;
                    if (xim >= 0 && xim < WW) {
                        int lpx = c3px + 8 + dx - 1;
                        int sp = c3h ^ ((lpx >> 2) & 1);
                        h16x8 v = *(const h16x8*)(h2s + lpx * 16 + sp * 8);
#pragma unroll
                        for (int q = 0; q < 4; ++q) {
                            h16x2 pv = { v[2 * q], v[2 * q + 1] };
                            d0 = __builtin_amdgcn_fdot2(pv, w3s[(0 + dx) * 8 + 4 * c3h + q], d0, false);
                            d1 = __builtin_amdgcn_fdot2(pv, w3s[(3 + dx) * 8 + 4 * c3h + q], d1, false);
                            d2 = __builtin_amdgcn_fdot2(pv, w3s[(6 + dx) * 8 + 4 * c3h + q], d2, false);
                        }
                    }
                }
            }
            if (i >= 5) {
                float accv = accC + d2;
                float full = accv + __shfl_xor(accv, 1) + w3bias;
                if (c3h == 0) {
                    float sg = 1.f / (1.f + expf(-full));
                    int o = (r2 - 1) * WW + X0 + c3px;
                    float tf = 0.7f * tgb[o] + 0.3f * sg;
                    outb[o] = fminf(fmaxf(tf, 0.f), 1.f);
                }
            }
            accC = accN + d1;
            accN = d0;
        }
        __syncthreads();
    }
}

extern "C" void kernel_launch(void* const* d_in, const int* in_sizes, int n_in,
                              void* d_out, int out_size, void* d_ws, size_t ws_size,
                              hipStream_t stream) {
    const float* I    = (const float*)d_in[0];
    const float* t0   = (const float*)d_in[1];
    const float* dark = (const float*)d_in[2];
    const float* A    = (const float*)d_in[3];
    const float* W1   = (const float*)d_in[4];
    const float* b1   = (const float*)d_in[5];
    const float* W2   = (const float*)d_in[6];
    const float* b2   = (const float*)d_in[7];
    const float* W3   = (const float*)d_in[8];
    const float* b3   = (const float*)d_in[9];
    float* out = (float*)d_out;
    float* ws  = (float*)d_ws;

    const size_t P = (size_t)BB * HW;       // 2M floats = 8 MB
    float* tg       = ws;                    // [0,P)   fp32
    _Float16* feats = (_Float16*)(ws + P);   // [P,5P)  fp16 [B][HW][8]
    float* g        = ws + 5 * P;            // [5P,6P)
    f32x4* hq       = (f32x4*)(ws + 6 * P);  // [6P,10P)
    f32x2* ab       = (f32x2*)(ws + 10 * P); // [10P,12P)
    f32x2* hab      = (f32x2*)(ws + 12 * P); // [12P,14P)
    _Float16* wf1   = (_Float16*)(ws + 14 * P);  // 3072 halves
    _Float16* wf2   = wf1 + 6 * 64 * 8;          // 4608 halves

    k_wprep<<<1, 64, 0, stream>>>(W1, W2, wf1, wf2);
    k_gray_hbox4<<<BB * HH, 256, 0, stream>>>(I, t0, dark, A, g, hq, feats);
    dim3 gv(WW / 256, BB, HH / SEG);
    k_vbox4_ab<<<gv, 256, 0, stream>>>(hq, ab);
    k_hbox2<<<BB * HH, 256, 0, stream>>>(ab, hab);
    k_vbox2_tg<<<gv, 256, 0, stream>>>(hab, g, tg, feats);

    dim3 gf(64, BB);                        // 32 y-tiles x 2 x-halves x 8 batches
    k_cnn_fused<<<gf, 512, 0, stream>>>(feats, wf1, wf2, b1, b2, W3, b3, tg, out);
}